// Round 12
// baseline (357.361 us; speedup 1.0000x reference)
//
#include <hip/hip_runtime.h>
#include <hip/hip_bf16.h>

#define NIMG 8
#define HW 56
#define CDIM 256
#define TOK (NIMG*HW*HW)        // 25088
#define NWIN 49
#define NPW (NIMG*NWIN)         // 392
#define ATT_SCALE 0.0625f       // 256^-0.5

typedef __attribute__((ext_vector_type(8))) short short8;
typedef __attribute__((ext_vector_type(4))) short short4v;
typedef __attribute__((ext_vector_type(4))) float f32x4;

// ---- workspace layout (bytes, 16B aligned) ----
static const size_t OFF_WQKV  = 0;           // 768x256 bf16
static const size_t OFF_WWO   = 393216;      // 256x256 bf16
static const size_t OFF_W1    = 524288;      // 1024x256 bf16
static const size_t OFF_W2    = 1048576;     // 256x1024 bf16
static const size_t OFF_XLN   = 1572864;     // 25088x256 bf16 (reused: ywo)
static const size_t OFF_QKV   = 14417920;    // 25088x768 bf16
static const size_t OFF_QKWIN = 52953088;    // 392x512 f32
static const size_t OFF_RIDX  = 53755904;    // 392x4 int
static const size_t OFF_ATTN  = 53762176;    // 25088x256 bf16 (reused: h2)

__device__ __forceinline__ float gelu_exact(float v) {
    return 0.5f * v * (1.f + erff(v * 0.70710678118654752f));
}
__device__ __forceinline__ short f2bs(float x) {
    __hip_bfloat16 h = __float2bfloat16(x);
    return *(short*)&h;
}
__device__ __forceinline__ float bs2f(short s) {
    return __uint_as_float(((unsigned)(unsigned short)s) << 16);
}
// async global->LDS, 16B per lane; LDS dest is wave-uniform base + lane*16
__device__ __forceinline__ void gld16(const short* g, short* l) {
    __builtin_amdgcn_global_load_lds(
        (const __attribute__((address_space(1))) void*)g,
        (__attribute__((address_space(3))) void*)l, 16, 0, 0);
}

// ---------------- batched weight transpose+cast: 4 weights in one launch ----------------
__global__ __launch_bounds__(256) void transpose_cast4_k(const float* __restrict__ s0,
                                                         const float* __restrict__ s1,
                                                         const float* __restrict__ s2,
                                                         const float* __restrict__ s3,
                                                         __hip_bfloat16* __restrict__ d0,
                                                         __hip_bfloat16* __restrict__ d1,
                                                         __hip_bfloat16* __restrict__ d2,
                                                         __hip_bfloat16* __restrict__ d3) {
    int b = blockIdx.x;
    const float* src; __hip_bfloat16* dst; int K, N, l;
    if (b < 192)      { src = s0; dst = d0; K = 256;  N = 768;  l = b; }
    else if (b < 256) { src = s1; dst = d1; K = 256;  N = 256;  l = b - 192; }
    else if (b < 512) { src = s2; dst = d2; K = 256;  N = 1024; l = b - 256; }
    else              { src = s3; dst = d3; K = 1024; N = 256;  l = b - 512; }
    int nx = N / 32;
    int n0 = (l % nx) * 32, k0 = (l / nx) * 32;
    __shared__ float t[32][33];
    int tx = threadIdx.x & 31, ty = threadIdx.x >> 5;   // 32 x 8
    #pragma unroll
    for (int i = 0; i < 32; i += 8)
        t[ty + i][tx] = src[(size_t)(k0 + ty + i) * N + n0 + tx];
    __syncthreads();
    #pragma unroll
    for (int i = 0; i < 32; i += 8)
        dst[(size_t)(n0 + ty + i) * K + k0 + tx] = __float2bfloat16(t[tx][ty + i]);
}

// ---------------- LayerNorm: wave per token, lane = 4 channels ----------------
__global__ __launch_bounds__(256) void ln_bf_k(const float* __restrict__ in,
                                               const float* __restrict__ g,
                                               const float* __restrict__ b,
                                               short* __restrict__ out, int remap) {
    int t = blockIdx.x * 4 + (threadIdx.x >> 6);
    int lane = threadIdx.x & 63;
    float4 v = *(const float4*)(in + (size_t)t * 256 + lane * 4);
    float s = v.x + v.y + v.z + v.w;
    float s2 = v.x * v.x + v.y * v.y + v.z * v.z + v.w * v.w;
    #pragma unroll
    for (int o = 32; o > 0; o >>= 1) {
        s  += __shfl_xor(s, o);
        s2 += __shfl_xor(s2, o);
    }
    float mu = s * (1.f / 256.f);
    float rstd = rsqrtf(s2 * (1.f / 256.f) - mu * mu + 1e-6f);
    float4 gv = *(const float4*)(g + lane * 4);
    float4 bv = *(const float4*)(b + lane * 4);
    short4v o;
    o[0] = f2bs((v.x - mu) * rstd * gv.x + bv.x);
    o[1] = f2bs((v.y - mu) * rstd * gv.y + bv.y);
    o[2] = f2bs((v.z - mu) * rstd * gv.z + bv.z);
    o[3] = f2bs((v.w - mu) * rstd * gv.w + bv.w);
    size_t tb;
    if (remap) {
        int n = t / 3136, rem = t % 3136, y = rem / 56, x = rem % 56;
        int p = (y >> 3) * 7 + (x >> 3);
        int si = (y & 7) * 8 + (x & 7);
        tb = (size_t)(n * 49 + p) * 64 + si;
    } else {
        tb = (size_t)t;
    }
    *(short4v*)(out + tb * 256 + lane * 4) = o;
}

// ---------------- unified 64Mx128N bf16 MFMA GEMM, BK=32 ----------------
// v4 (validated rounds 5/6/10): 256 threads (4 waves x 32x64), triple-buffered LDS,
//     prefetch distance 2, counted s_waitcnt vmcnt(3), one s_barrier per K-step,
//     XOR bank swizzle on staging source + fragment reads.
// MODE 0: bf16 out +bias (LDS-transpose epilogue) + fused per-window column means
// MODE 1: f32 out +bias+res (direct stores)
// MODE 2: bf16 out gelu(+bias) (LDS-transpose epilogue)
__device__ __forceinline__ void mfma_step(const short* As, const short* Bs,
                                          int wm, int wn, int l15, int swr,
                                          f32x4 acc[2][4]) {
    short8 af[2], bfr[4];
    #pragma unroll
    for (int i = 0; i < 2; ++i)
        af[i] = *(const short8*)&As[(wm + i * 16 + l15) * 32 + swr];
    #pragma unroll
    for (int j = 0; j < 4; ++j)
        bfr[j] = *(const short8*)&Bs[(wn + j * 16 + l15) * 32 + swr];
    #pragma unroll
    for (int i = 0; i < 2; ++i)
        #pragma unroll
        for (int j = 0; j < 4; ++j)
            acc[i][j] = __builtin_amdgcn_mfma_f32_16x16x32_bf16(af[i], bfr[j], acc[i][j], 0, 0, 0);
}

template<int MODE>
__global__ __launch_bounds__(256) void gemm64(const short* __restrict__ A,
                                              const short* __restrict__ Bt,
                                              const float* __restrict__ bias,
                                              const float* __restrict__ res,
                                              void* Cv, float* __restrict__ winptr,
                                              int M, int N, int K) {
    const int bn = blockIdx.x * 128;
    const int bm = blockIdx.y * 64;
    const int tid = threadIdx.x;
    const int wave = tid >> 6, lane = tid & 63;
    const int l15 = lane & 15, quad = lane >> 4;
    const int wm = (wave & 1) * 32, wn = (wave >> 1) * 64;

    __shared__ __align__(16) short smem[18432];   // 3 x (As 2048 | Bs 4096) shorts = 36KB

    f32x4 acc[2][4];
    #pragma unroll
    for (int i = 0; i < 2; ++i)
        #pragma unroll
        for (int j = 0; j < 4; ++j) acc[i][j] = (f32x4){0.f, 0.f, 0.f, 0.f};

    const int srow = lane >> 2;                               // 0..15
    const int scg  = ((lane & 3) ^ ((lane >> 3) & 3)) * 8;    // XOR-swizzled source colgroup
    const short* ga  = A  + (size_t)(bm + wave * 16 + srow) * K + scg;
    const short* gb0 = Bt + (size_t)(bn + wave * 16 + srow) * K + scg;
    const short* gb1 = gb0 + (size_t)64 * K;
    const int swr = (quad ^ ((l15 >> 1) & 3)) * 8;

    const int nt = K >> 5;

    // ---- prologue: stage tiles 0,1 -> buf0,buf1 ----
    {
        short* b0 = smem;
        gld16(ga,       b0 + wave * 512);
        gld16(gb0,      b0 + 2048 + wave * 512);
        gld16(gb1,      b0 + 4096 + wave * 512);
        short* b1 = smem + 6144;
        gld16(ga  + 32, b1 + wave * 512);
        gld16(gb0 + 32, b1 + 2048 + wave * 512);
        gld16(gb1 + 32, b1 + 4096 + wave * 512);
    }

    for (int t = 0; t < nt; ++t) {
        if (t == nt - 1) asm volatile("s_waitcnt vmcnt(0)" ::: "memory");
        else             asm volatile("s_waitcnt vmcnt(3)" ::: "memory");
        __builtin_amdgcn_s_barrier();
        asm volatile("" ::: "memory");
        if (t + 2 < nt) {
            short* b = smem + ((t + 2) % 3) * 6144;
            int kk = (t + 2) * 32;
            gld16(ga  + kk, b + wave * 512);
            gld16(gb0 + kk, b + 2048 + wave * 512);
            gld16(gb1 + kk, b + 4096 + wave * 512);
        }
        const short* As = smem + (t % 3) * 6144;
        mfma_step(As, As + 2048, wm, wn, l15, swr, acc);
    }

    // fused window column-means for routing (qkv GEMM only; BM=64 == one window)
    if (MODE == 0) {
        if (bn < 512) {
            float* wmean = (float*)&smem[12288];    // buf2 region, dead here
            #pragma unroll
            for (int j = 0; j < 4; ++j) {
                float s = 0.f;
                #pragma unroll
                for (int i = 0; i < 2; ++i)
                    #pragma unroll
                    for (int r = 0; r < 4; ++r) s += acc[i][j][r];
                s += __shfl_xor(s, 16);
                s += __shfl_xor(s, 32);
                if (quad == 0) wmean[wave * 64 + j * 16 + l15] = s;
            }
            __syncthreads();
            if (tid < 128) {
                int c = tid;
                float s = (c < 64) ? (wmean[c] + wmean[64 + c])
                                   : (wmean[64 + c] + wmean[128 + c]);
                int col = bn + c;
                if (col < 512)
                    winptr[(size_t)blockIdx.y * 512 + col] = s * (1.f / 64.f) + bias[col];
            }
        }
    }

    if (MODE == 1) {
        #pragma unroll
        for (int i = 0; i < 2; ++i) {
            int row = bm + wm + i * 16 + quad * 4;
            #pragma unroll
            for (int j = 0; j < 4; ++j) {
                int col = bn + wn + j * 16 + l15;
                float bia = bias[col];
                #pragma unroll
                for (int r = 0; r < 4; ++r) {
                    size_t idx = (size_t)(row + r) * N + col;
                    ((float*)Cv)[idx] = acc[i][j][r] + bia + res[idx];
                }
            }
        }
    } else {
        // all waves' LDS reads done before ep overlay reuse
        asm volatile("s_waitcnt lgkmcnt(0)" ::: "memory");
        __builtin_amdgcn_s_barrier();
        asm volatile("" ::: "memory");
        float biasv[4];
        #pragma unroll
        for (int j = 0; j < 4; ++j) biasv[j] = bias[bn + wn + j * 16 + l15];
        short* ep = &smem[wave * 1280];
        short* outp = (short*)Cv;
        #pragma unroll
        for (int p = 0; p < 2; ++p) {
            #pragma unroll
            for (int i = 0; i < 2; ++i)
                #pragma unroll
                for (int jj = 0; jj < 2; ++jj) {
                    int j = p * 2 + jj;
                    #pragma unroll
                    for (int r = 0; r < 4; ++r) {
                        float v = acc[i][j][r] + biasv[j];
                        if (MODE == 2) v = gelu_exact(v);
                        ep[(i * 16 + quad * 4 + r) * 40 + jj * 16 + l15] = f2bs(v);
                    }
                }
            __builtin_amdgcn_s_waitcnt(0);
            int c = lane & 3;
            #pragma unroll
            for (int rr = 0; rr < 2; ++rr) {
                int row = rr * 16 + (lane >> 2);
                short8 v = *(const short8*)&ep[row * 40 + c * 8];
                *(short8*)&outp[(size_t)(bm + wm + row) * N + bn + wn + p * 32 + c * 8] = v;
            }
            __builtin_amdgcn_s_waitcnt(0);
        }
    }
}

// ---------------- wo GEMM (N=K=256) + residual + fused LN2 -> out f32 + h2 bf16 ----------
__global__ __launch_bounds__(256) void gemm_woln_k(const short* __restrict__ A,
                                                   const short* __restrict__ Bt,
                                                   const float* __restrict__ bias,
                                                   const float* __restrict__ res,
                                                   const float* __restrict__ g2,
                                                   const float* __restrict__ b2,
                                                   float* __restrict__ out,
                                                   short* __restrict__ h2) {
    const int K = 256;
    const int bm = blockIdx.x * 64;
    const int tid = threadIdx.x;
    const int wave = tid >> 6, lane = tid & 63;
    const int l15 = lane & 15, quad = lane >> 4;
    const int wn = wave * 64;

    __shared__ __align__(16) short smem[30720];   // 3 x (As 2048 | Bs 8192) shorts = 60KB

    f32x4 acc[4][4];
    #pragma unroll
    for (int i = 0; i < 4; ++i)
        #pragma unroll
        for (int j = 0; j < 4; ++j) acc[i][j] = (f32x4){0.f, 0.f, 0.f, 0.f};

    const int srow = lane >> 2;
    const int scg  = ((lane & 3) ^ ((lane >> 3) & 3)) * 8;
    const short* ga  = A  + (size_t)(bm + wave * 16 + srow) * K + scg;
    const short* gb  = Bt + (size_t)(wn + srow) * K + scg;
    const int swr = (quad ^ ((l15 >> 1) & 3)) * 8;

    const int nt = 8;

    #define WOLN_STAGE(T) do {                                              \
        short* _b = smem + ((T) % 3) * 10240;                               \
        int _kk = (T) * 32;                                                 \
        gld16(ga + _kk, _b + wave * 512);                                   \
        _Pragma("unroll")                                                   \
        for (int X = 0; X < 4; ++X)                                         \
            gld16(gb + (size_t)X * 16 * K + _kk,                            \
                  _b + 2048 + (wave * 4 + X) * 512);                        \
    } while (0)

    WOLN_STAGE(0);
    WOLN_STAGE(1);

    for (int t = 0; t < nt; ++t) {
        if (t == nt - 1) asm volatile("s_waitcnt vmcnt(0)" ::: "memory");
        else             asm volatile("s_waitcnt vmcnt(5)" ::: "memory");
        __builtin_amdgcn_s_barrier();
        asm volatile("" ::: "memory");
        if (t + 2 < nt) WOLN_STAGE(t + 2);
        const short* As = smem + (t % 3) * 10240;
        const short* Bs = As + 2048;
        short8 af[4], bfr[4];
        #pragma unroll
        for (int i = 0; i < 4; ++i)
            af[i] = *(const short8*)&As[(i * 16 + l15) * 32 + swr];
        #pragma unroll
        for (int j = 0; j < 4; ++j)
            bfr[j] = *(const short8*)&Bs[(wn + j * 16 + l15) * 32 + swr];
        #pragma unroll
        for (int i = 0; i < 4; ++i)
            #pragma unroll
            for (int j = 0; j < 4; ++j)
                acc[i][j] = __builtin_amdgcn_mfma_f32_16x16x32_bf16(af[i], bfr[j], acc[i][j], 0, 0, 0);
    }
    #undef WOLN_STAGE

    // ---- epilogue: residual add + out write, keep y in acc ----
    float bv4[4];
    #pragma unroll
    for (int j = 0; j < 4; ++j) bv4[j] = bias[wn + j * 16 + l15];
    #pragma unroll
    for (int i = 0; i < 4; ++i) {
        int row = bm + i * 16 + quad * 4;
        #pragma unroll
        for (int j = 0; j < 4; ++j) {
            int col = wn + j * 16 + l15;
            #pragma unroll
            for (int r = 0; r < 4; ++r) {
                size_t idx = (size_t)(row + r) * 256 + col;
                float y = acc[i][j][r] + bv4[j] + res[idx];
                out[idx] = y;
                acc[i][j][r] = y;
            }
        }
    }

    // ---- row stats ----
    float* S1 = (float*)smem;           // [4][64]
    float* S2 = (float*)smem + 256;     // [4][64]
    #pragma unroll
    for (int i = 0; i < 4; ++i) {
        #pragma unroll
        for (int r = 0; r < 4; ++r) {
            float s1 = 0.f, s2 = 0.f;
            #pragma unroll
            for (int j = 0; j < 4; ++j) {
                float y = acc[i][j][r];
                s1 += y; s2 += y * y;
            }
            #pragma unroll
            for (int o = 1; o < 16; o <<= 1) {
                s1 += __shfl_xor(s1, o);
                s2 += __shfl_xor(s2, o);
            }
            if (l15 == 0) {
                int R = i * 16 + quad * 4 + r;
                S1[wave * 64 + R] = s1;
                S2[wave * 64 + R] = s2;
            }
        }
    }
    __syncthreads();

    // ---- normalize + h2 ----
    float gv4[4], bb4[4];
    #pragma unroll
    for (int j = 0; j < 4; ++j) {
        gv4[j] = g2[wn + j * 16 + l15];
        bb4[j] = b2[wn + j * 16 + l15];
    }
    #pragma unroll
    for (int i = 0; i < 4; ++i) {
        #pragma unroll
        for (int r = 0; r < 4; ++r) {
            int R = i * 16 + quad * 4 + r;
            float t1 = S1[R] + S1[64 + R] + S1[128 + R] + S1[192 + R];
            float t2 = S2[R] + S2[64 + R] + S2[128 + R] + S2[192 + R];
            float mu = t1 * (1.f / 256.f);
            float rstd = rsqrtf(t2 * (1.f / 256.f) - mu * mu + 1e-6f);
            #pragma unroll
            for (int j = 0; j < 4; ++j) {
                int col = wn + j * 16 + l15;
                h2[(size_t)(bm + R) * 256 + col] =
                    f2bs((acc[i][j][r] - mu) * rstd * gv4[j] + bb4[j]);
            }
        }
    }
}

// ---------------- fused MLP v4 (barrier-free K-loops): out += gelu(h2@W1+b1)@W2 + b2 ----
// Block = 64 tokens, 4 waves. Per quarter Q (256 hidden):
//   stage1 (2 chunks of 128): acc1 via DIRECT global->register fragment loads
//     (h2 A-frags + W1 B-frags; W1 L2-resident, h2 tile L1-sized) -- no LDS staging,
//     no barriers in the K-loop; compiler pipelines the unrolled loads.
//   G write: identical to r10 (proven swizzle).
//   stage2: A-frags from G (r10-proven swizzled reads), W2 B-frags DIRECT from global.
// Cross-wave sync: exactly 2 __syncthreads() per quarter (G handoff) = 8 per block
// (vs ~96 full-drain barriers in v3 at 1.5 blocks/CU occupancy).
// LDS: G only = 32KB.
__global__ __launch_bounds__(256) void mlp_fused_k(const short* __restrict__ h2,
                                                   const short* __restrict__ w1t,
                                                   const float* __restrict__ b1,
                                                   const short* __restrict__ w2t,
                                                   const float* __restrict__ b2,
                                                   float* __restrict__ out) {
    const int bm = blockIdx.x * 64;
    const int tid = threadIdx.x;
    const int wave = tid >> 6, lane = tid & 63;
    const int l15 = lane & 15, quad = lane >> 4;
    const int wm = (wave & 1) * 32, wn = (wave >> 1) * 64;   // stage-1 mapping
    const int wn2 = wave * 64;                               // stage-2 col mapping

    __shared__ __align__(16) short G[16384];   // [64][256] bf16, XOR-swizzled = 32KB

    f32x4 acc2[4][4];
    #pragma unroll
    for (int i = 0; i < 4; ++i)
        #pragma unroll
        for (int j = 0; j < 4; ++j) acc2[i][j] = (f32x4){0.f, 0.f, 0.f, 0.f};

    const int sg = (l15 & 3) ^ (l15 >> 2);    // G row-swizzle key for row = i*16+l15

    for (int Q = 0; Q < 4; ++Q) {
        // ---------- stage 1: G = gelu(h2 @ W1_quarter + b1), 128 cols per ch ----------
        #pragma unroll
        for (int ch = 0; ch < 2; ++ch) {
            const int H0 = Q * 256 + ch * 128;
            f32x4 acc1[2][4];
            #pragma unroll
            for (int i = 0; i < 2; ++i)
                #pragma unroll
                for (int j = 0; j < 4; ++j) acc1[i][j] = (f32x4){0.f, 0.f, 0.f, 0.f};
            #pragma unroll
            for (int t = 0; t < 8; ++t) {
                short8 af[2], bfr[4];
                #pragma unroll
                for (int i = 0; i < 2; ++i)
                    af[i] = *(const short8*)&h2[(size_t)(bm + wm + i * 16 + l15) * 256
                                                + t * 32 + quad * 8];
                #pragma unroll
                for (int j = 0; j < 4; ++j)
                    bfr[j] = *(const short8*)&w1t[(size_t)(H0 + wn + j * 16 + l15) * 256
                                                  + t * 32 + quad * 8];
                #pragma unroll
                for (int i = 0; i < 2; ++i)
                    #pragma unroll
                    for (int j = 0; j < 4; ++j)
                        acc1[i][j] = __builtin_amdgcn_mfma_f32_16x16x32_bf16(af[i], bfr[j], acc1[i][j], 0, 0, 0);
            }
            // gelu + swizzled G write (identical to r10-proven path)
            float b1v[4];
            #pragma unroll
            for (int j = 0; j < 4; ++j) b1v[j] = b1[H0 + wn + j * 16 + l15];
            #pragma unroll
            for (int i = 0; i < 2; ++i) {
                int row = wm + i * 16 + quad * 4;
                #pragma unroll
                for (int j = 0; j < 4; ++j) {
                    int colL = ch * 128 + wn + j * 16 + l15;
                    #pragma unroll
                    for (int r = 0; r < 4; ++r) {
                        int rw = row + r;
                        int sw = r ^ quad;   // == (rw&3)^((rw>>2)&3)
                        int cs = (colL & ~31) | ((((colL >> 3) & 3) ^ sw) << 3) | (colL & 7);
                        G[rw * 256 + cs] = f2bs(gelu_exact(acc1[i][j][r] + b1v[j]));
                    }
                }
            }
        }
        __syncthreads();   // all G writes visible to all waves

        // ---------- stage 2: acc2 += G @ W2_quarter (A from G, B direct global) --------
        #pragma unroll
        for (int s = 0; s < 8; ++s) {
            short8 af[4], bfr[4];
            #pragma unroll
            for (int i = 0; i < 4; ++i)
                af[i] = *(const short8*)&G[(i * 16 + l15) * 256 + s * 32 + ((quad ^ sg) << 3)];
            #pragma unroll
            for (int j = 0; j < 4; ++j)
                bfr[j] = *(const short8*)&w2t[(size_t)(wn2 + j * 16 + l15) * 1024
                                              + Q * 256 + s * 32 + quad * 8];
            #pragma unroll
            for (int i = 0; i < 4; ++i)
                #pragma unroll
                for (int j = 0; j < 4; ++j)
                    acc2[i][j] = __builtin_amdgcn_mfma_f32_16x16x32_bf16(af[i], bfr[j], acc2[i][j], 0, 0, 0);
        }
        __syncthreads();   // all G reads retired before next quarter overwrites
    }

    // ---------- epilogue: out += acc2 + b2 (residual in place) ----------
    float b2v[4];
    #pragma unroll
    for (int j = 0; j < 4; ++j) b2v[j] = b2[wn2 + j * 16 + l15];
    #pragma unroll
    for (int i = 0; i < 4; ++i) {
        int row = bm + i * 16 + quad * 4;
        #pragma unroll
        for (int j = 0; j < 4; ++j) {
            int col = wn2 + j * 16 + l15;
            #pragma unroll
            for (int r = 0; r < 4; ++r) {
                size_t idx = (size_t)(row + r) * 256 + col;
                out[idx] = acc2[i][j][r] + b2v[j] + out[idx];
            }
        }
    }
}

// ---------------- routing top-k ----------------
__global__ __launch_bounds__(64) void route_k(const float* __restrict__ qkwin,
                                              int* __restrict__ ridx) {
    int w = blockIdx.x;
    int n = w / 49;
    int tid = threadIdx.x;
    __shared__ float qv[256];
    __shared__ float lg[49];
    for (int i = tid; i < 256; i += 64) qv[i] = qkwin[(size_t)w * 512 + i] * ATT_SCALE;
    __syncthreads();
    if (tid < 49) {
        const float* kp = qkwin + (size_t)(n * 49 + tid) * 512 + 256;
        float d = 0.f;
        for (int cc = 0; cc < 256; ++cc) d += qv[cc] * kp[cc];
        lg[tid] = d;
    }
    __syncthreads();
    if (tid == 0) {
        #pragma unroll
        for (int t = 0; t < 4; ++t) {
            float best = -1e30f; int bi = 0;
            for (int j = 0; j < 49; ++j)
                if (lg[j] > best) { best = lg[j]; bi = j; }
            lg[bi] = -1e30f;
            ridx[w * 4 + t] = bi;
        }
    }
}

// ---------------- MFMA attention v2: S^T/O^T operand order, Ps overlays Ks ----------------
__global__ __launch_bounds__(256) void attn_mfma_k(const short* __restrict__ qkv,
                                                   const int* __restrict__ ridx,
                                                   short* __restrict__ attn) {
    const int blk = blockIdx.x;
    const int w = blk >> 3, h = blk & 7;
    const int n = w / 49;
    const int tid = threadIdx.x;
    const int wave = tid >> 6, lane = tid & 63;
    const int l15 = lane & 15, quad = lane >> 4;

    __shared__ __align__(16) short smem[25344];   // 50.7KB total
    short* Vt = smem;           // [32][264]
    short* Ks = smem + 8448;    // [256][40] — dead after S
    short* Ps = smem + 8448;    // [4][16][264] — overlays Ks
    __shared__ int rs4[4];
    if (tid < 4) rs4[tid] = ridx[w * 4 + tid];
    __syncthreads();

    // stage K: [key][dim] pad 40
    {
        int s = tid >> 2, kq = (tid & 3) * 8;
        #pragma unroll
        for (int u = 0; u < 4; ++u) {
            int key = u * 64 + s;
            const short* src = qkv + ((size_t)(n * 49 + rs4[u]) * 64 + s) * 768 + 256 + h * 32 + kq;
            *(short8*)&Ks[key * 40 + kq] = *(const short8*)src;
        }
    }
    // stage V transposed, pair-packed b32 writes
    {
        int kp = tid & 127, dh = tid >> 7;
        int k0 = kp * 2;
        int t = k0 >> 6, s = k0 & 63;
        const short* src0 = qkv + ((size_t)(n * 49 + rs4[t]) * 64 + s) * 768 + 512 + h * 32 + dh * 16;
        const short* src1 = src0 + 768;
        short8 a0 = *(const short8*)src0, a1 = *(const short8*)(src0 + 8);
        short8 b0 = *(const short8*)src1, b1 = *(const short8*)(src1 + 8);
        #pragma unroll
        for (int d = 0; d < 8; ++d) {
            *(unsigned*)&Vt[(dh * 16 + d) * 264 + k0] =
                (unsigned)(unsigned short)a0[d] | ((unsigned)(unsigned short)b0[d] << 16);
            *(unsigned*)&Vt[(dh * 16 + 8 + d) * 264 + k0] =
                (unsigned)(unsigned short)a1[d] | ((unsigned)(unsigned short)b1[d] << 16);
        }
    }
    __syncthreads();

    const short* qp = qkv + ((size_t)w * 64 + wave * 16 + l15) * 768 + h * 32 + quad * 8;
    short8 qf = *(const short8*)qp;

    f32x4 st[16];
    #pragma unroll
    for (int j = 0; j < 16; ++j) {
        short8 kf = *(const short8*)&Ks[(j * 16 + l15) * 40 + quad * 8];
        st[j] = __builtin_amdgcn_mfma_f32_16x16x32_bf16(kf, qf, (f32x4){0.f, 0.f, 0.f, 0.f}, 0, 0, 0);
    }

    float mx = -1e30f;
    #pragma unroll
    for (int j = 0; j < 16; ++j)
        #pragma unroll
        for (int r = 0; r < 4; ++r) mx = fmaxf(mx, st[j][r]);
    mx = fmaxf(mx, __shfl_xor(mx, 16));
    mx = fmaxf(mx, __shfl_xor(mx, 32));

    __syncthreads();

    short* pw = &Ps[wave * 16 * 264];
    float sum = 0.f;
    #pragma unroll
    for (int j = 0; j < 16; ++j) {
        short4v pv;
        #pragma unroll
        for (int r = 0; r < 4; ++r) {
            float p = __expf((st[j][r] - mx) * ATT_SCALE);
            sum += p;
            pv[r] = f2bs(p);
        }
        *(short4v*)&pw[l15 * 264 + j * 16 + quad * 4] = pv;
    }
    sum += __shfl_xor(sum, 16);
    sum += __shfl_xor(sum, 32);
    float inv = 1.f / sum;
    __builtin_amdgcn_s_waitcnt(0);

    f32x4 oc[2] = {(f32x4){0.f,0.f,0.f,0.f}, (f32x4){0.f,0.f,0.f,0.f}};
    #pragma unroll
    for (int kk = 0; kk < 8; ++kk) {
        short8 pf = *(const short8*)&pw[l15 * 264 + kk * 32 + quad * 8];
        #pragma unroll
        for (int jj = 0; jj < 2; ++jj) {
            short8 vf = *(const short8*)&Vt[(jj * 16 + l15) * 264 + kk * 32 + quad * 8];
            oc[jj] = __builtin_amdgcn_mfma_f32_16x16x32_bf16(vf, pf, oc[jj], 0, 0, 0);
        }
    }

    short* op = attn + ((size_t)w * 64 + wave * 16 + l15) * 256 + h * 32;
    #pragma unroll
    for (int jj = 0; jj < 2; ++jj) {
        short4v o4;
        #pragma unroll
        for (int r = 0; r < 4; ++r) o4[r] = f2bs(oc[jj][r] * inv);
        *(short4v*)&op[jj * 16 + quad * 4] = o4;
    }
}

// ---------------- LePE 5x5 dwconv + combine (vectorized 8-ch per thread) ----------------
__global__ __launch_bounds__(256) void lepe_k(const short* __restrict__ qkv,
                                              const short* __restrict__ attn,
                                              const float* __restrict__ lw,
                                              const float* __restrict__ lb,
                                              short* __restrict__ ywo) {
    int t = blockIdx.x * 8 + (threadIdx.x >> 5);
    int c0 = (threadIdx.x & 31) * 8;
    int n = t / 3136, rem = t % 3136, y = rem / 56, x = rem % 56;
    float sum[8];
    {
        float4 b0 = *(const float4*)(lb + c0), b1 = *(const float4*)(lb + c0 + 4);
        sum[0] = b0.x; sum[1] = b0.y; sum[2] = b0.z; sum[3] = b0.w;
        sum[4] = b1.x; sum[5] = b1.y; sum[6] = b1.z; sum[7] = b1.w;
    }
    #pragma unroll
    for (int ky = 0; ky < 5; ++ky) {
        int yy = y + ky - 2;
        if ((unsigned)yy >= 56u) continue;
        #pragma unroll
        for (int kx = 0; kx < 5; ++kx) {
            int xx = x + kx - 2;
            if ((unsigned)xx >= 56u) continue;
            int p = (yy >> 3) * 7 + (xx >> 3);
            int si = (yy & 7) * 8 + (xx & 7);
            short8 v = *(const short8*)(qkv + ((size_t)(n * 49 + p) * 64 + si) * 768 + 512 + c0);
            const float* wp = lw + (ky * 5 + kx) * 256 + c0;
            float4 w0 = *(const float4*)wp, w1 = *(const float4*)(wp + 4);
            sum[0] += bs2f(v[0]) * w0.x; sum[1] += bs2f(v[1]) * w0.y;
            sum[2] += bs2f(v[2]) * w0.z; sum[3] += bs2f(v[3]) * w0.w;
            sum[4] += bs2f(v[4]) * w1.x; sum[5] += bs2f(v[5]) * w1.y;
            sum[6] += bs2f(v[6]) * w1.z; sum[7] += bs2f(v[7]) * w1.w;
        }
    }
    int p0 = (y >> 3) * 7 + (x >> 3);
    int s0 = (y & 7) * 8 + (x & 7);
    short8 a = *(const short8*)(attn + ((size_t)(n * 49 + p0) * 64 + s0) * 256 + c0);
    short8 o;
    #pragma unroll
    for (int i = 0; i < 8; ++i) o[i] = f2bs(sum[i] + bs2f(a[i]));
    *(short8*)(ywo + (size_t)t * 256 + c0) = o;
}

extern "C" void kernel_launch(void* const* d_in, const int* in_sizes, int n_in,
                              void* d_out, int out_size, void* d_ws, size_t ws_size,
                              hipStream_t stream) {
    const float* x      = (const float*)d_in[0];
    const float* ln1_g  = (const float*)d_in[1];
    const float* ln1_b  = (const float*)d_in[2];
    const float* qkv_w  = (const float*)d_in[3];
    const float* qkv_b  = (const float*)d_in[4];
    const float* lepe_w = (const float*)d_in[5];
    const float* lepe_b = (const float*)d_in[6];
    const float* wo_w   = (const float*)d_in[7];
    const float* wo_b   = (const float*)d_in[8];
    const float* ln2_g  = (const float*)d_in[9];
    const float* ln2_b  = (const float*)d_in[10];
    const float* mlp_w1 = (const float*)d_in[11];
    const float* mlp_b1 = (const float*)d_in[12];
    const float* mlp_w2 = (const float*)d_in[13];
    const float* mlp_b2 = (const float*)d_in[14];
    float* out = (float*)d_out;

    char* ws = (char*)d_ws;
    __hip_bfloat16* wqkvT = (__hip_bfloat16*)(ws + OFF_WQKV);
    __hip_bfloat16* wwoT  = (__hip_bfloat16*)(ws + OFF_WWO);
    __hip_bfloat16* w1T   = (__hip_bfloat16*)(ws + OFF_W1);
    __hip_bfloat16* w2T   = (__hip_bfloat16*)(ws + OFF_W2);
    short* xln   = (short*)(ws + OFF_XLN);
    short* qkvb  = (short*)(ws + OFF_QKV);
    float* qkwin = (float*)(ws + OFF_QKWIN);
    int*   ridx  = (int*)(ws + OFF_RIDX);
    short* attnb = (short*)(ws + OFF_ATTN);
    short* ywo   = (short*)(ws + OFF_XLN);    // reuse
    short* h2    = (short*)(ws + OFF_ATTN);   // reuse

    // 0. all weights -> bf16 transposed (N x K), one launch
    transpose_cast4_k<<<768, 256, 0, stream>>>(qkv_w, wo_w, mlp_w1, mlp_w2,
                                               wqkvT, wwoT, w1T, w2T);
    // 1. LN1 -> xln bf16 (window order)
    ln_bf_k<<<TOK/4, 256, 0, stream>>>(x, ln1_g, ln1_b, xln, 1);
    // 2. qkv GEMM -> bf16, fused window means for routing
    gemm64<0><<<dim3(6, 392), 256, 0, stream>>>(xln, (const short*)wqkvT,
                                                qkv_b, nullptr, qkvb, qkwin, TOK, 768, 256);
    // 3. routing
    route_k<<<NPW, 64, 0, stream>>>(qkwin, ridx);
    // 4. attention (MFMA) -> bf16
    attn_mfma_k<<<NPW * 8, 256, 0, stream>>>(qkvb, ridx, attnb);
    // 5. lepe + combine -> ywo bf16 (image order)
    lepe_k<<<TOK/8, 256, 0, stream>>>(qkvb, attnb, lepe_w, lepe_b, ywo);
    // 6. wo GEMM + x residual + fused LN2 -> out f32, h2 bf16
    gemm_woln_k<<<TOK/64, 256, 0, stream>>>(ywo, (const short*)wwoT, wo_b, x,
                                            ln2_g, ln2_b, out, h2);
    // 7. fused MLP v4 (barrier-free K-loops): out += gelu(h2@W1+b1)@W2 + b2
    mlp_fused_k<<<TOK/64, 256, 0, stream>>>(h2, (const short*)w1T, mlp_b1,
                                            (const short*)w2T, mlp_b2, out);
}

// Round 13
// 275.752 us; speedup vs baseline: 1.2959x; 1.2959x over previous
//
#include <hip/hip_runtime.h>
#include <hip/hip_bf16.h>

#define NIMG 8
#define HW 56
#define CDIM 256
#define TOK (NIMG*HW*HW)        // 25088
#define NWIN 49
#define NPW (NIMG*NWIN)         // 392
#define ATT_SCALE 0.0625f       // 256^-0.5

typedef __attribute__((ext_vector_type(8))) short short8;
typedef __attribute__((ext_vector_type(4))) short short4v;
typedef __attribute__((ext_vector_type(4))) float f32x4;

// ---- workspace layout (bytes, 16B aligned) ----
static const size_t OFF_WQKV  = 0;           // 768x256 bf16
static const size_t OFF_WWO   = 393216;      // 256x256 bf16
static const size_t OFF_W1    = 524288;      // 1024x256 bf16
static const size_t OFF_W2    = 1048576;     // 256x1024 bf16
static const size_t OFF_XLN   = 1572864;     // 25088x256 bf16 (reused: ywo)
static const size_t OFF_QKV   = 14417920;    // 25088x768 bf16
static const size_t OFF_QKWIN = 52953088;    // 392x512 f32
static const size_t OFF_RIDX  = 53755904;    // 392x4 int
static const size_t OFF_ATTN  = 53762176;    // 25088x256 bf16 (reused: h2)

__device__ __forceinline__ float gelu_exact(float v) {
    return 0.5f * v * (1.f + erff(v * 0.70710678118654752f));
}
__device__ __forceinline__ short f2bs(float x) {
    __hip_bfloat16 h = __float2bfloat16(x);
    return *(short*)&h;
}
__device__ __forceinline__ float bs2f(short s) {
    return __uint_as_float(((unsigned)(unsigned short)s) << 16);
}
// async global->LDS, 16B per lane; LDS dest is wave-uniform base + lane*16
__device__ __forceinline__ void gld16(const short* g, short* l) {
    __builtin_amdgcn_global_load_lds(
        (const __attribute__((address_space(1))) void*)g,
        (__attribute__((address_space(3))) void*)l, 16, 0, 0);
}

// ---------------- batched weight transpose+cast: 4 weights in one launch ----------------
__global__ __launch_bounds__(256) void transpose_cast4_k(const float* __restrict__ s0,
                                                         const float* __restrict__ s1,
                                                         const float* __restrict__ s2,
                                                         const float* __restrict__ s3,
                                                         __hip_bfloat16* __restrict__ d0,
                                                         __hip_bfloat16* __restrict__ d1,
                                                         __hip_bfloat16* __restrict__ d2,
                                                         __hip_bfloat16* __restrict__ d3) {
    int b = blockIdx.x;
    const float* src; __hip_bfloat16* dst; int K, N, l;
    if (b < 192)      { src = s0; dst = d0; K = 256;  N = 768;  l = b; }
    else if (b < 256) { src = s1; dst = d1; K = 256;  N = 256;  l = b - 192; }
    else if (b < 512) { src = s2; dst = d2; K = 256;  N = 1024; l = b - 256; }
    else              { src = s3; dst = d3; K = 1024; N = 256;  l = b - 512; }
    int nx = N / 32;
    int n0 = (l % nx) * 32, k0 = (l / nx) * 32;
    __shared__ float t[32][33];
    int tx = threadIdx.x & 31, ty = threadIdx.x >> 5;   // 32 x 8
    #pragma unroll
    for (int i = 0; i < 32; i += 8)
        t[ty + i][tx] = src[(size_t)(k0 + ty + i) * N + n0 + tx];
    __syncthreads();
    #pragma unroll
    for (int i = 0; i < 32; i += 8)
        dst[(size_t)(n0 + ty + i) * K + k0 + tx] = __float2bfloat16(t[tx][ty + i]);
}

// ---------------- LayerNorm: wave per token, lane = 4 channels ----------------
__global__ __launch_bounds__(256) void ln_bf_k(const float* __restrict__ in,
                                               const float* __restrict__ g,
                                               const float* __restrict__ b,
                                               short* __restrict__ out, int remap) {
    int t = blockIdx.x * 4 + (threadIdx.x >> 6);
    int lane = threadIdx.x & 63;
    float4 v = *(const float4*)(in + (size_t)t * 256 + lane * 4);
    float s = v.x + v.y + v.z + v.w;
    float s2 = v.x * v.x + v.y * v.y + v.z * v.z + v.w * v.w;
    #pragma unroll
    for (int o = 32; o > 0; o >>= 1) {
        s  += __shfl_xor(s, o);
        s2 += __shfl_xor(s2, o);
    }
    float mu = s * (1.f / 256.f);
    float rstd = rsqrtf(s2 * (1.f / 256.f) - mu * mu + 1e-6f);
    float4 gv = *(const float4*)(g + lane * 4);
    float4 bv = *(const float4*)(b + lane * 4);
    short4v o;
    o[0] = f2bs((v.x - mu) * rstd * gv.x + bv.x);
    o[1] = f2bs((v.y - mu) * rstd * gv.y + bv.y);
    o[2] = f2bs((v.z - mu) * rstd * gv.z + bv.z);
    o[3] = f2bs((v.w - mu) * rstd * gv.w + bv.w);
    size_t tb;
    if (remap) {
        int n = t / 3136, rem = t % 3136, y = rem / 56, x = rem % 56;
        int p = (y >> 3) * 7 + (x >> 3);
        int si = (y & 7) * 8 + (x & 7);
        tb = (size_t)(n * 49 + p) * 64 + si;
    } else {
        tb = (size_t)t;
    }
    *(short4v*)(out + tb * 256 + lane * 4) = o;
}

// ---------------- unified 64Mx128N bf16 MFMA GEMM, BK=32 ----------------
// v4 (validated rounds 5/6/10): 256 threads (4 waves x 32x64), triple-buffered LDS,
//     prefetch distance 2, counted s_waitcnt vmcnt(3), one s_barrier per K-step,
//     XOR bank swizzle on staging source + fragment reads.
// MODE 0: bf16 out +bias (LDS-transpose epilogue) + fused per-window column means
// MODE 1: f32 out +bias+res (direct stores)
// MODE 2: bf16 out gelu(+bias) (LDS-transpose epilogue)
__device__ __forceinline__ void mfma_step(const short* As, const short* Bs,
                                          int wm, int wn, int l15, int swr,
                                          f32x4 acc[2][4]) {
    short8 af[2], bfr[4];
    #pragma unroll
    for (int i = 0; i < 2; ++i)
        af[i] = *(const short8*)&As[(wm + i * 16 + l15) * 32 + swr];
    #pragma unroll
    for (int j = 0; j < 4; ++j)
        bfr[j] = *(const short8*)&Bs[(wn + j * 16 + l15) * 32 + swr];
    #pragma unroll
    for (int i = 0; i < 2; ++i)
        #pragma unroll
        for (int j = 0; j < 4; ++j)
            acc[i][j] = __builtin_amdgcn_mfma_f32_16x16x32_bf16(af[i], bfr[j], acc[i][j], 0, 0, 0);
}

template<int MODE>
__global__ __launch_bounds__(256) void gemm64(const short* __restrict__ A,
                                              const short* __restrict__ Bt,
                                              const float* __restrict__ bias,
                                              const float* __restrict__ res,
                                              void* Cv, float* __restrict__ winptr,
                                              int M, int N, int K) {
    const int bn = blockIdx.x * 128;
    const int bm = blockIdx.y * 64;
    const int tid = threadIdx.x;
    const int wave = tid >> 6, lane = tid & 63;
    const int l15 = lane & 15, quad = lane >> 4;
    const int wm = (wave & 1) * 32, wn = (wave >> 1) * 64;

    __shared__ __align__(16) short smem[18432];   // 3 x (As 2048 | Bs 4096) shorts = 36KB

    f32x4 acc[2][4];
    #pragma unroll
    for (int i = 0; i < 2; ++i)
        #pragma unroll
        for (int j = 0; j < 4; ++j) acc[i][j] = (f32x4){0.f, 0.f, 0.f, 0.f};

    const int srow = lane >> 2;                               // 0..15
    const int scg  = ((lane & 3) ^ ((lane >> 3) & 3)) * 8;    // XOR-swizzled source colgroup
    const short* ga  = A  + (size_t)(bm + wave * 16 + srow) * K + scg;
    const short* gb0 = Bt + (size_t)(bn + wave * 16 + srow) * K + scg;
    const short* gb1 = gb0 + (size_t)64 * K;
    const int swr = (quad ^ ((l15 >> 1) & 3)) * 8;

    const int nt = K >> 5;

    // ---- prologue: stage tiles 0,1 -> buf0,buf1 ----
    {
        short* b0 = smem;
        gld16(ga,       b0 + wave * 512);
        gld16(gb0,      b0 + 2048 + wave * 512);
        gld16(gb1,      b0 + 4096 + wave * 512);
        short* b1 = smem + 6144;
        gld16(ga  + 32, b1 + wave * 512);
        gld16(gb0 + 32, b1 + 2048 + wave * 512);
        gld16(gb1 + 32, b1 + 4096 + wave * 512);
    }

    for (int t = 0; t < nt; ++t) {
        if (t == nt - 1) asm volatile("s_waitcnt vmcnt(0)" ::: "memory");
        else             asm volatile("s_waitcnt vmcnt(3)" ::: "memory");
        __builtin_amdgcn_s_barrier();
        asm volatile("" ::: "memory");
        if (t + 2 < nt) {
            short* b = smem + ((t + 2) % 3) * 6144;
            int kk = (t + 2) * 32;
            gld16(ga  + kk, b + wave * 512);
            gld16(gb0 + kk, b + 2048 + wave * 512);
            gld16(gb1 + kk, b + 4096 + wave * 512);
        }
        const short* As = smem + (t % 3) * 6144;
        mfma_step(As, As + 2048, wm, wn, l15, swr, acc);
    }

    // fused window column-means for routing (qkv GEMM only; BM=64 == one window)
    if (MODE == 0) {
        if (bn < 512) {
            float* wmean = (float*)&smem[12288];    // buf2 region, dead here
            #pragma unroll
            for (int j = 0; j < 4; ++j) {
                float s = 0.f;
                #pragma unroll
                for (int i = 0; i < 2; ++i)
                    #pragma unroll
                    for (int r = 0; r < 4; ++r) s += acc[i][j][r];
                s += __shfl_xor(s, 16);
                s += __shfl_xor(s, 32);
                if (quad == 0) wmean[wave * 64 + j * 16 + l15] = s;
            }
            __syncthreads();
            if (tid < 128) {
                int c = tid;
                float s = (c < 64) ? (wmean[c] + wmean[64 + c])
                                   : (wmean[64 + c] + wmean[128 + c]);
                int col = bn + c;
                if (col < 512)
                    winptr[(size_t)blockIdx.y * 512 + col] = s * (1.f / 64.f) + bias[col];
            }
        }
    }

    if (MODE == 1) {
        #pragma unroll
        for (int i = 0; i < 2; ++i) {
            int row = bm + wm + i * 16 + quad * 4;
            #pragma unroll
            for (int j = 0; j < 4; ++j) {
                int col = bn + wn + j * 16 + l15;
                float bia = bias[col];
                #pragma unroll
                for (int r = 0; r < 4; ++r) {
                    size_t idx = (size_t)(row + r) * N + col;
                    ((float*)Cv)[idx] = acc[i][j][r] + bia + res[idx];
                }
            }
        }
    } else {
        // all waves' LDS reads done before ep overlay reuse
        asm volatile("s_waitcnt lgkmcnt(0)" ::: "memory");
        __builtin_amdgcn_s_barrier();
        asm volatile("" ::: "memory");
        float biasv[4];
        #pragma unroll
        for (int j = 0; j < 4; ++j) biasv[j] = bias[bn + wn + j * 16 + l15];
        short* ep = &smem[wave * 1280];
        short* outp = (short*)Cv;
        #pragma unroll
        for (int p = 0; p < 2; ++p) {
            #pragma unroll
            for (int i = 0; i < 2; ++i)
                #pragma unroll
                for (int jj = 0; jj < 2; ++jj) {
                    int j = p * 2 + jj;
                    #pragma unroll
                    for (int r = 0; r < 4; ++r) {
                        float v = acc[i][j][r] + biasv[j];
                        if (MODE == 2) v = gelu_exact(v);
                        ep[(i * 16 + quad * 4 + r) * 40 + jj * 16 + l15] = f2bs(v);
                    }
                }
            __builtin_amdgcn_s_waitcnt(0);
            int c = lane & 3;
            #pragma unroll
            for (int rr = 0; rr < 2; ++rr) {
                int row = rr * 16 + (lane >> 2);
                short8 v = *(const short8*)&ep[row * 40 + c * 8];
                *(short8*)&outp[(size_t)(bm + wm + row) * N + bn + wn + p * 32 + c * 8] = v;
            }
            __builtin_amdgcn_s_waitcnt(0);
        }
    }
}

// ---------------- wo GEMM (N=K=256) + residual + fused LN2 -> out f32 + h2 bf16 ----------
__global__ __launch_bounds__(256) void gemm_woln_k(const short* __restrict__ A,
                                                   const short* __restrict__ Bt,
                                                   const float* __restrict__ bias,
                                                   const float* __restrict__ res,
                                                   const float* __restrict__ g2,
                                                   const float* __restrict__ b2,
                                                   float* __restrict__ out,
                                                   short* __restrict__ h2) {
    const int K = 256;
    const int bm = blockIdx.x * 64;
    const int tid = threadIdx.x;
    const int wave = tid >> 6, lane = tid & 63;
    const int l15 = lane & 15, quad = lane >> 4;
    const int wn = wave * 64;

    __shared__ __align__(16) short smem[30720];   // 3 x (As 2048 | Bs 8192) shorts = 60KB

    f32x4 acc[4][4];
    #pragma unroll
    for (int i = 0; i < 4; ++i)
        #pragma unroll
        for (int j = 0; j < 4; ++j) acc[i][j] = (f32x4){0.f, 0.f, 0.f, 0.f};

    const int srow = lane >> 2;
    const int scg  = ((lane & 3) ^ ((lane >> 3) & 3)) * 8;
    const short* ga  = A  + (size_t)(bm + wave * 16 + srow) * K + scg;
    const short* gb  = Bt + (size_t)(wn + srow) * K + scg;
    const int swr = (quad ^ ((l15 >> 1) & 3)) * 8;

    const int nt = 8;

    #define WOLN_STAGE(T) do {                                              \
        short* _b = smem + ((T) % 3) * 10240;                               \
        int _kk = (T) * 32;                                                 \
        gld16(ga + _kk, _b + wave * 512);                                   \
        _Pragma("unroll")                                                   \
        for (int X = 0; X < 4; ++X)                                         \
            gld16(gb + (size_t)X * 16 * K + _kk,                            \
                  _b + 2048 + (wave * 4 + X) * 512);                        \
    } while (0)

    WOLN_STAGE(0);
    WOLN_STAGE(1);

    for (int t = 0; t < nt; ++t) {
        if (t == nt - 1) asm volatile("s_waitcnt vmcnt(0)" ::: "memory");
        else             asm volatile("s_waitcnt vmcnt(5)" ::: "memory");
        __builtin_amdgcn_s_barrier();
        asm volatile("" ::: "memory");
        if (t + 2 < nt) WOLN_STAGE(t + 2);
        const short* As = smem + (t % 3) * 10240;
        const short* Bs = As + 2048;
        short8 af[4], bfr[4];
        #pragma unroll
        for (int i = 0; i < 4; ++i)
            af[i] = *(const short8*)&As[(i * 16 + l15) * 32 + swr];
        #pragma unroll
        for (int j = 0; j < 4; ++j)
            bfr[j] = *(const short8*)&Bs[(wn + j * 16 + l15) * 32 + swr];
        #pragma unroll
        for (int i = 0; i < 4; ++i)
            #pragma unroll
            for (int j = 0; j < 4; ++j)
                acc[i][j] = __builtin_amdgcn_mfma_f32_16x16x32_bf16(af[i], bfr[j], acc[i][j], 0, 0, 0);
    }
    #undef WOLN_STAGE

    // ---- epilogue: residual add + out write, keep y in acc ----
    float bv4[4];
    #pragma unroll
    for (int j = 0; j < 4; ++j) bv4[j] = bias[wn + j * 16 + l15];
    #pragma unroll
    for (int i = 0; i < 4; ++i) {
        int row = bm + i * 16 + quad * 4;
        #pragma unroll
        for (int j = 0; j < 4; ++j) {
            int col = wn + j * 16 + l15;
            #pragma unroll
            for (int r = 0; r < 4; ++r) {
                size_t idx = (size_t)(row + r) * 256 + col;
                float y = acc[i][j][r] + bv4[j] + res[idx];
                out[idx] = y;
                acc[i][j][r] = y;
            }
        }
    }

    // ---- row stats ----
    float* S1 = (float*)smem;           // [4][64]
    float* S2 = (float*)smem + 256;     // [4][64]
    #pragma unroll
    for (int i = 0; i < 4; ++i) {
        #pragma unroll
        for (int r = 0; r < 4; ++r) {
            float s1 = 0.f, s2 = 0.f;
            #pragma unroll
            for (int j = 0; j < 4; ++j) {
                float y = acc[i][j][r];
                s1 += y; s2 += y * y;
            }
            #pragma unroll
            for (int o = 1; o < 16; o <<= 1) {
                s1 += __shfl_xor(s1, o);
                s2 += __shfl_xor(s2, o);
            }
            if (l15 == 0) {
                int R = i * 16 + quad * 4 + r;
                S1[wave * 64 + R] = s1;
                S2[wave * 64 + R] = s2;
            }
        }
    }
    __syncthreads();

    // ---- normalize + h2 ----
    float gv4[4], bb4[4];
    #pragma unroll
    for (int j = 0; j < 4; ++j) {
        gv4[j] = g2[wn + j * 16 + l15];
        bb4[j] = b2[wn + j * 16 + l15];
    }
    #pragma unroll
    for (int i = 0; i < 4; ++i) {
        #pragma unroll
        for (int r = 0; r < 4; ++r) {
            int R = i * 16 + quad * 4 + r;
            float t1 = S1[R] + S1[64 + R] + S1[128 + R] + S1[192 + R];
            float t2 = S2[R] + S2[64 + R] + S2[128 + R] + S2[192 + R];
            float mu = t1 * (1.f / 256.f);
            float rstd = rsqrtf(t2 * (1.f / 256.f) - mu * mu + 1e-6f);
            #pragma unroll
            for (int j = 0; j < 4; ++j) {
                int col = wn + j * 16 + l15;
                h2[(size_t)(bm + R) * 256 + col] =
                    f2bs((acc[i][j][r] - mu) * rstd * gv4[j] + bb4[j]);
            }
        }
    }
}

// ---------------- fused MLP v5: out += gelu(h2@W1+b1)@W2 + b2 ----------------
// Base = r10-proven v3. ONE change: stage-2's staging is wave-private (wave w writes
// and reads only chunks wave*4..wave*4+3; G is frozen during stage 2), so its 8
// in-loop __syncthreads() are replaced by the wave-local __builtin_amdgcn_s_waitcnt(0)
// idiom (proven in attn_mfma_k Ps handoff + gemm64 epilogue) with prefetch-after-wait
// double buffering. Stage 1 (cross-wave staging) is byte-identical to r10.
// Barriers: ~96 -> ~64 per block; stage-2 loads pipeline under MFMAs.
// LDS: G 32KB | stg 32KB = 64KB.
__global__ __launch_bounds__(256) void mlp_fused_k(const short* __restrict__ h2,
                                                   const short* __restrict__ w1t,
                                                   const float* __restrict__ b1,
                                                   const short* __restrict__ w2t,
                                                   const float* __restrict__ b2,
                                                   float* __restrict__ out) {
    const int bm = blockIdx.x * 64;
    const int tid = threadIdx.x;
    const int wave = tid >> 6, lane = tid & 63;
    const int l15 = lane & 15, quad = lane >> 4;
    const int wm = (wave & 1) * 32, wn = (wave >> 1) * 64;   // stage-1 mapping
    const int wn2 = wave * 64;                               // stage-2 col mapping

    __shared__ __align__(16) short smem[32768];   // G[64][256] 32KB | stg 32KB
    short* G   = smem;
    short* stg = smem + 16384;

    f32x4 acc2[4][4];
    #pragma unroll
    for (int i = 0; i < 4; ++i)
        #pragma unroll
        for (int j = 0; j < 4; ++j) acc2[i][j] = (f32x4){0.f, 0.f, 0.f, 0.f};

    const int srow = lane >> 2;
    const int scg  = ((lane & 3) ^ ((lane >> 3) & 3)) * 8;
    const int swr  = (quad ^ ((l15 >> 1) & 3)) * 8;
    const int sg   = (l15 & 3) ^ (l15 >> 2);      // G row-swizzle key for row = i*16+l15
    const short* gA = h2 + (size_t)(bm + wave * 16 + srow) * 256 + scg;

    for (int Q = 0; Q < 4; ++Q) {
        // ---------- stage 1: G = gelu(h2 @ W1_quarter + b1), 128 cols per ch ----------
        // (byte-identical to r10-proven v3: conservative __syncthreads sync)
        for (int ch = 0; ch < 2; ++ch) {
            const int H0 = Q * 256 + ch * 128;
            const short* gB0 = w1t + (size_t)(H0 + wave * 16 + srow) * 256 + scg;
            const short* gB1 = gB0 + (size_t)64 * 256;
            gld16(gA,  stg + wave * 512);
            gld16(gB0, stg + 2048 + wave * 512);
            gld16(gB1, stg + 4096 + wave * 512);
            f32x4 acc1[2][4];
            #pragma unroll
            for (int i = 0; i < 2; ++i)
                #pragma unroll
                for (int j = 0; j < 4; ++j) acc1[i][j] = (f32x4){0.f, 0.f, 0.f, 0.f};
            for (int t = 0; t < 8; ++t) {
                __syncthreads();    // drains vmcnt+lgkmcnt: tile-t staged, prior reads retired
                if (t + 1 < 8) {
                    short* b = stg + ((t + 1) & 1) * 6144;
                    int kk = (t + 1) * 32;
                    gld16(gA  + kk, b + wave * 512);
                    gld16(gB0 + kk, b + 2048 + wave * 512);
                    gld16(gB1 + kk, b + 4096 + wave * 512);
                }
                const short* As = stg + (t & 1) * 6144;
                mfma_step(As, As + 2048, wm, wn, l15, swr, acc1);
            }
            // gelu + swizzled G write (G region disjoint from stg)
            float b1v[4];
            #pragma unroll
            for (int j = 0; j < 4; ++j) b1v[j] = b1[H0 + wn + j * 16 + l15];
            #pragma unroll
            for (int i = 0; i < 2; ++i) {
                int row = wm + i * 16 + quad * 4;
                #pragma unroll
                for (int j = 0; j < 4; ++j) {
                    int colL = ch * 128 + wn + j * 16 + l15;
                    #pragma unroll
                    for (int r = 0; r < 4; ++r) {
                        int rw = row + r;
                        int sw = r ^ quad;   // == (rw&3)^((rw>>2)&3)
                        int cs = (colL & ~31) | ((((colL >> 3) & 3) ^ sw) << 3) | (colL & 7);
                        G[rw * 256 + cs] = f2bs(gelu_exact(acc1[i][j][r] + b1v[j]));
                    }
                }
            }
            __syncthreads();   // all stg reads + G writes of this ch retired/visible
        }

        // ---------- stage 2: acc2 += G @ W2_quarter (wave-private staging) ----------
        // W2 chunks wave*4..wave*4+3 are written AND read only by this wave; G is
        // frozen (no writes until the quarter-end barrier). So sync is wave-local:
        // __builtin_amdgcn_s_waitcnt(0) before reading own tile; prefetch after wait.
        {
            const short* gW = w2t + (size_t)(wn2 + srow) * 1024 + Q * 256 + scg;
            #pragma unroll
            for (int X = 0; X < 4; ++X)
                gld16(gW + (size_t)X * 16 * 1024, stg + (wave * 4 + X) * 512);
            for (int s = 0; s < 8; ++s) {
                __builtin_amdgcn_s_waitcnt(0);   // wave-local: own tile-s loads + prior ds_reads done
                if (s + 1 < 8) {
                    short* b = stg + ((s + 1) & 1) * 8192;
                    int kk = (s + 1) * 32;
                    #pragma unroll
                    for (int X = 0; X < 4; ++X)
                        gld16(gW + (size_t)X * 16 * 1024 + kk, b + (wave * 4 + X) * 512);
                }
                const short* Bs = stg + (s & 1) * 8192;
                short8 af[4], bfr[4];
                #pragma unroll
                for (int i = 0; i < 4; ++i)
                    af[i] = *(const short8*)&G[(i * 16 + l15) * 256 + s * 32 + ((quad ^ sg) << 3)];
                #pragma unroll
                for (int j = 0; j < 4; ++j)
                    bfr[j] = *(const short8*)&Bs[(wave * 4 + j) * 512 + l15 * 32 + swr];
                #pragma unroll
                for (int i = 0; i < 4; ++i)
                    #pragma unroll
                    for (int j = 0; j < 4; ++j)
                        acc2[i][j] = __builtin_amdgcn_mfma_f32_16x16x32_bf16(af[i], bfr[j], acc2[i][j], 0, 0, 0);
            }
            __syncthreads();   // all waves' G + stg reads retired before next quarter overwrites
        }
    }

    // ---------- epilogue: out += acc2 + b2 (residual in place) ----------
    float b2v[4];
    #pragma unroll
    for (int j = 0; j < 4; ++j) b2v[j] = b2[wn2 + j * 16 + l15];
    #pragma unroll
    for (int i = 0; i < 4; ++i) {
        int row = bm + i * 16 + quad * 4;
        #pragma unroll
        for (int j = 0; j < 4; ++j) {
            int col = wn2 + j * 16 + l15;
            #pragma unroll
            for (int r = 0; r < 4; ++r) {
                size_t idx = (size_t)(row + r) * 256 + col;
                out[idx] = acc2[i][j][r] + b2v[j] + out[idx];
            }
        }
    }
}

// ---------------- routing top-k ----------------
__global__ __launch_bounds__(64) void route_k(const float* __restrict__ qkwin,
                                              int* __restrict__ ridx) {
    int w = blockIdx.x;
    int n = w / 49;
    int tid = threadIdx.x;
    __shared__ float qv[256];
    __shared__ float lg[49];
    for (int i = tid; i < 256; i += 64) qv[i] = qkwin[(size_t)w * 512 + i] * ATT_SCALE;
    __syncthreads();
    if (tid < 49) {
        const float* kp = qkwin + (size_t)(n * 49 + tid) * 512 + 256;
        float d = 0.f;
        for (int cc = 0; cc < 256; ++cc) d += qv[cc] * kp[cc];
        lg[tid] = d;
    }
    __syncthreads();
    if (tid == 0) {
        #pragma unroll
        for (int t = 0; t < 4; ++t) {
            float best = -1e30f; int bi = 0;
            for (int j = 0; j < 49; ++j)
                if (lg[j] > best) { best = lg[j]; bi = j; }
            lg[bi] = -1e30f;
            ridx[w * 4 + t] = bi;
        }
    }
}

// ---------------- MFMA attention v2: S^T/O^T operand order, Ps overlays Ks ----------------
__global__ __launch_bounds__(256) void attn_mfma_k(const short* __restrict__ qkv,
                                                   const int* __restrict__ ridx,
                                                   short* __restrict__ attn) {
    const int blk = blockIdx.x;
    const int w = blk >> 3, h = blk & 7;
    const int n = w / 49;
    const int tid = threadIdx.x;
    const int wave = tid >> 6, lane = tid & 63;
    const int l15 = lane & 15, quad = lane >> 4;

    __shared__ __align__(16) short smem[25344];   // 50.7KB total
    short* Vt = smem;           // [32][264]
    short* Ks = smem + 8448;    // [256][40] — dead after S
    short* Ps = smem + 8448;    // [4][16][264] — overlays Ks
    __shared__ int rs4[4];
    if (tid < 4) rs4[tid] = ridx[w * 4 + tid];
    __syncthreads();

    // stage K: [key][dim] pad 40
    {
        int s = tid >> 2, kq = (tid & 3) * 8;
        #pragma unroll
        for (int u = 0; u < 4; ++u) {
            int key = u * 64 + s;
            const short* src = qkv + ((size_t)(n * 49 + rs4[u]) * 64 + s) * 768 + 256 + h * 32 + kq;
            *(short8*)&Ks[key * 40 + kq] = *(const short8*)src;
        }
    }
    // stage V transposed, pair-packed b32 writes
    {
        int kp = tid & 127, dh = tid >> 7;
        int k0 = kp * 2;
        int t = k0 >> 6, s = k0 & 63;
        const short* src0 = qkv + ((size_t)(n * 49 + rs4[t]) * 64 + s) * 768 + 512 + h * 32 + dh * 16;
        const short* src1 = src0 + 768;
        short8 a0 = *(const short8*)src0, a1 = *(const short8*)(src0 + 8);
        short8 b0 = *(const short8*)src1, b1 = *(const short8*)(src1 + 8);
        #pragma unroll
        for (int d = 0; d < 8; ++d) {
            *(unsigned*)&Vt[(dh * 16 + d) * 264 + k0] =
                (unsigned)(unsigned short)a0[d] | ((unsigned)(unsigned short)b0[d] << 16);
            *(unsigned*)&Vt[(dh * 16 + 8 + d) * 264 + k0] =
                (unsigned)(unsigned short)a1[d] | ((unsigned)(unsigned short)b1[d] << 16);
        }
    }
    __syncthreads();

    const short* qp = qkv + ((size_t)w * 64 + wave * 16 + l15) * 768 + h * 32 + quad * 8;
    short8 qf = *(const short8*)qp;

    f32x4 st[16];
    #pragma unroll
    for (int j = 0; j < 16; ++j) {
        short8 kf = *(const short8*)&Ks[(j * 16 + l15) * 40 + quad * 8];
        st[j] = __builtin_amdgcn_mfma_f32_16x16x32_bf16(kf, qf, (f32x4){0.f, 0.f, 0.f, 0.f}, 0, 0, 0);
    }

    float mx = -1e30f;
    #pragma unroll
    for (int j = 0; j < 16; ++j)
        #pragma unroll
        for (int r = 0; r < 4; ++r) mx = fmaxf(mx, st[j][r]);
    mx = fmaxf(mx, __shfl_xor(mx, 16));
    mx = fmaxf(mx, __shfl_xor(mx, 32));

    __syncthreads();

    short* pw = &Ps[wave * 16 * 264];
    float sum = 0.f;
    #pragma unroll
    for (int j = 0; j < 16; ++j) {
        short4v pv;
        #pragma unroll
        for (int r = 0; r < 4; ++r) {
            float p = __expf((st[j][r] - mx) * ATT_SCALE);
            sum += p;
            pv[r] = f2bs(p);
        }
        *(short4v*)&pw[l15 * 264 + j * 16 + quad * 4] = pv;
    }
    sum += __shfl_xor(sum, 16);
    sum += __shfl_xor(sum, 32);
    float inv = 1.f / sum;
    __builtin_amdgcn_s_waitcnt(0);

    f32x4 oc[2] = {(f32x4){0.f,0.f,0.f,0.f}, (f32x4){0.f,0.f,0.f,0.f}};
    #pragma unroll
    for (int kk = 0; kk < 8; ++kk) {
        short8 pf = *(const short8*)&pw[l15 * 264 + kk * 32 + quad * 8];
        #pragma unroll
        for (int jj = 0; jj < 2; ++jj) {
            short8 vf = *(const short8*)&Vt[(jj * 16 + l15) * 264 + kk * 32 + quad * 8];
            oc[jj] = __builtin_amdgcn_mfma_f32_16x16x32_bf16(vf, pf, oc[jj], 0, 0, 0);
        }
    }

    short* op = attn + ((size_t)w * 64 + wave * 16 + l15) * 256 + h * 32;
    #pragma unroll
    for (int jj = 0; jj < 2; ++jj) {
        short4v o4;
        #pragma unroll
        for (int r = 0; r < 4; ++r) o4[r] = f2bs(oc[jj][r] * inv);
        *(short4v*)&op[jj * 16 + quad * 4] = o4;
    }
}

// ---------------- LePE 5x5 dwconv + combine (vectorized 8-ch per thread) ----------------
__global__ __launch_bounds__(256) void lepe_k(const short* __restrict__ qkv,
                                              const short* __restrict__ attn,
                                              const float* __restrict__ lw,
                                              const float* __restrict__ lb,
                                              short* __restrict__ ywo) {
    int t = blockIdx.x * 8 + (threadIdx.x >> 5);
    int c0 = (threadIdx.x & 31) * 8;
    int n = t / 3136, rem = t % 3136, y = rem / 56, x = rem % 56;
    float sum[8];
    {
        float4 b0 = *(const float4*)(lb + c0), b1 = *(const float4*)(lb + c0 + 4);
        sum[0] = b0.x; sum[1] = b0.y; sum[2] = b0.z; sum[3] = b0.w;
        sum[4] = b1.x; sum[5] = b1.y; sum[6] = b1.z; sum[7] = b1.w;
    }
    #pragma unroll
    for (int ky = 0; ky < 5; ++ky) {
        int yy = y + ky - 2;
        if ((unsigned)yy >= 56u) continue;
        #pragma unroll
        for (int kx = 0; kx < 5; ++kx) {
            int xx = x + kx - 2;
            if ((unsigned)xx >= 56u) continue;
            int p = (yy >> 3) * 7 + (xx >> 3);
            int si = (yy & 7) * 8 + (xx & 7);
            short8 v = *(const short8*)(qkv + ((size_t)(n * 49 + p) * 64 + si) * 768 + 512 + c0);
            const float* wp = lw + (ky * 5 + kx) * 256 + c0;
            float4 w0 = *(const float4*)wp, w1 = *(const float4*)(wp + 4);
            sum[0] += bs2f(v[0]) * w0.x; sum[1] += bs2f(v[1]) * w0.y;
            sum[2] += bs2f(v[2]) * w0.z; sum[3] += bs2f(v[3]) * w0.w;
            sum[4] += bs2f(v[4]) * w1.x; sum[5] += bs2f(v[5]) * w1.y;
            sum[6] += bs2f(v[6]) * w1.z; sum[7] += bs2f(v[7]) * w1.w;
        }
    }
    int p0 = (y >> 3) * 7 + (x >> 3);
    int s0 = (y & 7) * 8 + (x & 7);
    short8 a = *(const short8*)(attn + ((size_t)(n * 49 + p0) * 64 + s0) * 256 + c0);
    short8 o;
    #pragma unroll
    for (int i = 0; i < 8; ++i) o[i] = f2bs(sum[i] + bs2f(a[i]));
    *(short8*)(ywo + (size_t)t * 256 + c0) = o;
}

extern "C" void kernel_launch(void* const* d_in, const int* in_sizes, int n_in,
                              void* d_out, int out_size, void* d_ws, size_t ws_size,
                              hipStream_t stream) {
    const float* x      = (const float*)d_in[0];
    const float* ln1_g  = (const float*)d_in[1];
    const float* ln1_b  = (const float*)d_in[2];
    const float* qkv_w  = (const float*)d_in[3];
    const float* qkv_b  = (const float*)d_in[4];
    const float* lepe_w = (const float*)d_in[5];
    const float* lepe_b = (const float*)d_in[6];
    const float* wo_w   = (const float*)d_in[7];
    const float* wo_b   = (const float*)d_in[8];
    const float* ln2_g  = (const float*)d_in[9];
    const float* ln2_b  = (const float*)d_in[10];
    const float* mlp_w1 = (const float*)d_in[11];
    const float* mlp_b1 = (const float*)d_in[12];
    const float* mlp_w2 = (const float*)d_in[13];
    const float* mlp_b2 = (const float*)d_in[14];
    float* out = (float*)d_out;

    char* ws = (char*)d_ws;
    __hip_bfloat16* wqkvT = (__hip_bfloat16*)(ws + OFF_WQKV);
    __hip_bfloat16* wwoT  = (__hip_bfloat16*)(ws + OFF_WWO);
    __hip_bfloat16* w1T   = (__hip_bfloat16*)(ws + OFF_W1);
    __hip_bfloat16* w2T   = (__hip_bfloat16*)(ws + OFF_W2);
    short* xln   = (short*)(ws + OFF_XLN);
    short* qkvb  = (short*)(ws + OFF_QKV);
    float* qkwin = (float*)(ws + OFF_QKWIN);
    int*   ridx  = (int*)(ws + OFF_RIDX);
    short* attnb = (short*)(ws + OFF_ATTN);
    short* ywo   = (short*)(ws + OFF_XLN);    // reuse
    short* h2    = (short*)(ws + OFF_ATTN);   // reuse

    // 0. all weights -> bf16 transposed (N x K), one launch
    transpose_cast4_k<<<768, 256, 0, stream>>>(qkv_w, wo_w, mlp_w1, mlp_w2,
                                               wqkvT, wwoT, w1T, w2T);
    // 1. LN1 -> xln bf16 (window order)
    ln_bf_k<<<TOK/4, 256, 0, stream>>>(x, ln1_g, ln1_b, xln, 1);
    // 2. qkv GEMM -> bf16, fused window means for routing
    gemm64<0><<<dim3(6, 392), 256, 0, stream>>>(xln, (const short*)wqkvT,
                                                qkv_b, nullptr, qkvb, qkwin, TOK, 768, 256);
    // 3. routing
    route_k<<<NPW, 64, 0, stream>>>(qkwin, ridx);
    // 4. attention (MFMA) -> bf16
    attn_mfma_k<<<NPW * 8, 256, 0, stream>>>(qkvb, ridx, attnb);
    // 5. lepe + combine -> ywo bf16 (image order)
    lepe_k<<<TOK/8, 256, 0, stream>>>(qkvb, attnb, lepe_w, lepe_b, ywo);
    // 6. wo GEMM + x residual + fused LN2 -> out f32, h2 bf16
    gemm_woln_k<<<TOK/64, 256, 0, stream>>>(ywo, (const short*)wwoT, wo_b, x,
                                            ln2_g, ln2_b, out, h2);
    // 7. fused MLP v5 (wave-private stage-2 sync): out += gelu(h2@W1+b1)@W2 + b2
    mlp_fused_k<<<TOK/64, 256, 0, stream>>>(h2, (const short*)w1T, mlp_b1,
                                            (const short*)w2T, mlp_b2, out);
}